// Round 5
// baseline (2225.323 us; speedup 1.0000x reference)
//
#include <hip/hip_runtime.h>
#include <math.h>

#define NPTS 8192
#define KNN 20
#define CAP 256

static __device__ __forceinline__ unsigned long long umin64(unsigned long long a, unsigned long long b) {
    return a < b ? a : b;
}

// ---------------- row squared norms: bit-faithful replica of np.sum(x*x, -1) ----------------
template<int C>
__global__ void rowsq_np_kernel(const float* __restrict__ X, int ld, float* __restrict__ x2) {
#pragma clang fp contract(off)
    int i = blockIdx.x * blockDim.x + threadIdx.x;
    if (i >= NPTS) return;
    const float* row = X + (long)i * ld;
    float res;
    if (C < 8) {
        res = 0.f;
        for (int c = 0; c < C; ++c) res += row[c] * row[c];
    } else {
        float r[8];
#pragma unroll
        for (int j = 0; j < 8; ++j) r[j] = row[j] * row[j];
        int p = 8;
        for (; p < C - (C % 8); p += 8)
#pragma unroll
            for (int j = 0; j < 8; ++j) r[j] += row[p + j] * row[p + j];
        res = ((r[0] + r[1]) + (r[2] + r[3])) + ((r[4] + r[5]) + (r[6] + r[7]));
        for (; p < C; ++p) res += row[p] * row[p];
    }
    x2[i] = res;
}

// ---------------- pairwise distance (fp32), K-chunked GEMM structure ----------------
// Bit-identical accumulation to round-4: one fmaf accumulator per element, k strictly
// ascending; pad lanes contribute fmaf(0,0,acc) == acc exactly.
template<int C>
__global__ __launch_bounds__(256) void dist_kernel(const float* __restrict__ X, int ld,
                                                   const float* __restrict__ x2,
                                                   float* __restrict__ dist, int i0base) {
    __shared__ float As[16][68];
    __shared__ float Bs[16][68];
    const int tid = threadIdx.x;
    const int i0 = i0base + blockIdx.y * 64;
    const int j0 = blockIdx.x * 64;
    const int ty = tid >> 4, tx = tid & 15;

    float acc[4][4];
#pragma unroll
    for (int a = 0; a < 4; ++a)
#pragma unroll
        for (int b = 0; b < 4; ++b) acc[a][b] = 0.f;

    for (int k0 = 0; k0 < C; k0 += 16) {
        {
            int t = tid;
            int r = t >> 4, c = t & 15;
            // 256 threads cover 16 cols x 16 rows per pass; 4 passes cover r=0..63
#pragma unroll
            for (int q = 0; q < 4; ++q) {
                int rr = r + 16 * q;
                As[c][rr] = (k0 + c < C) ? X[(long)(i0 + rr) * ld + k0 + c] : 0.f;
                Bs[c][rr] = (k0 + c < C) ? X[(long)(j0 + rr) * ld + k0 + c] : 0.f;
            }
        }
        __syncthreads();
#pragma unroll
        for (int kk = 0; kk < 16; ++kk) {
            float4 a4 = *(const float4*)&As[kk][ty * 4];
            float4 b4 = *(const float4*)&Bs[kk][tx * 4];
            float av[4] = {a4.x, a4.y, a4.z, a4.w};
            float bv[4] = {b4.x, b4.y, b4.z, b4.w};
#pragma unroll
            for (int ii = 0; ii < 4; ++ii)
#pragma unroll
                for (int jj = 0; jj < 4; ++jj)
                    acc[ii][jj] = fmaf(av[ii], bv[jj], acc[ii][jj]);
        }
        __syncthreads();
    }

    float xj[4];
#pragma unroll
    for (int jj = 0; jj < 4; ++jj) xj[jj] = x2[j0 + tx * 4 + jj];
#pragma unroll
    for (int ii = 0; ii < 4; ++ii) {
        int rloc = blockIdx.y * 64 + ty * 4 + ii;
        float xi = x2[i0base + rloc];
        float4 o;
        o.x = (xi + xj[0]) - 2.f * acc[ii][0];
        o.y = (xi + xj[1]) - 2.f * acc[ii][1];
        o.z = (xi + xj[2]) - 2.f * acc[ii][2];
        o.w = (xi + xj[3]) - 2.f * acc[ii][3];
        *(float4*)&dist[(long)rloc * NPTS + j0 + tx * 4] = o;
    }
}

// ---------------- exact top-K via 2-level radix-select (ascending by (dist,index)) ----------------
// Selects the identical set+order as 20-round extraction: monotonic u32 key, rank-20 bin by
// top byte, refine by 2nd byte, collect all candidates with prefix16 <= bound (cap 256,
// exact full-scan fallback on overflow), then exact (key,idx) extraction over candidates.
__global__ __launch_bounds__(256) void topk_kernel(const float* __restrict__ dist, int* __restrict__ idx_out,
                                                   int rowbase) {
    __shared__ unsigned int keys[NPTS];
    __shared__ unsigned int hist[256];
    __shared__ unsigned long long cand[CAP];
    __shared__ int s_b1, s_cb1, s_b2, s_ncand;
    __shared__ unsigned long long wred[4];
    const int tid = threadIdx.x;
    const int row = rowbase + blockIdx.x;
    const float* drow = dist + (long)blockIdx.x * NPTS;

    for (int m = 0; m < NPTS / 256; ++m) {
        int j = tid + 256 * m;
        unsigned u = __float_as_uint(drow[j]);
        keys[j] = (u & 0x80000000u) ? ~u : (u | 0x80000000u);
    }
    hist[tid] = 0;
    __syncthreads();

    for (int m = 0; m < NPTS / 256; ++m)
        atomicAdd(&hist[keys[tid + 256 * m] >> 24], 1u);
    __syncthreads();

    if (tid < 64) {
        unsigned c0 = hist[tid * 4], c1 = hist[tid * 4 + 1], c2 = hist[tid * 4 + 2], c3 = hist[tid * 4 + 3];
        unsigned gs = c0 + c1 + c2 + c3;
        unsigned pre = gs;
#pragma unroll
        for (int o = 1; o < 64; o <<= 1) { unsigned v = __shfl_up(pre, (unsigned)o); if (tid >= o) pre += v; }
        unsigned cb = pre - gs;
        int b = -1; unsigned cbv = 0;
#pragma unroll
        for (int q = 0; q < 4; ++q) {
            unsigned h = (q == 0) ? c0 : (q == 1) ? c1 : (q == 2) ? c2 : c3;
            if (b < 0 && cb < KNN && cb + h >= KNN) { b = tid * 4 + q; cbv = cb; }
            cb += h;
        }
        if (b >= 0) { s_b1 = b; s_cb1 = (int)cbv; }
    }
    __syncthreads();
    const int b1 = s_b1, cb1 = s_cb1;
    hist[tid] = 0;
    __syncthreads();

    for (int m = 0; m < NPTS / 256; ++m) {
        unsigned u = keys[tid + 256 * m];
        if ((int)(u >> 24) == b1) atomicAdd(&hist[(u >> 16) & 0xFFu], 1u);
    }
    __syncthreads();

    if (tid < 64) {
        const unsigned rank2 = (unsigned)(KNN - cb1);   // >=1
        unsigned c0 = hist[tid * 4], c1 = hist[tid * 4 + 1], c2 = hist[tid * 4 + 2], c3 = hist[tid * 4 + 3];
        unsigned gs = c0 + c1 + c2 + c3;
        unsigned pre = gs;
#pragma unroll
        for (int o = 1; o < 64; o <<= 1) { unsigned v = __shfl_up(pre, (unsigned)o); if (tid >= o) pre += v; }
        unsigned cb = pre - gs;
        int b = -1;
#pragma unroll
        for (int q = 0; q < 4; ++q) {
            unsigned h = (q == 0) ? c0 : (q == 1) ? c1 : (q == 2) ? c2 : c3;
            if (b < 0 && cb < rank2 && cb + h >= rank2) b = tid * 4 + q;
            cb += h;
        }
        if (b >= 0) s_b2 = b;
        if (tid == 0) s_ncand = 0;
    }
    __syncthreads();
    const unsigned bound16 = ((unsigned)b1 << 8) | (unsigned)s_b2;

    for (int m = 0; m < NPTS / 256; ++m) {
        int j = tid + 256 * m;
        unsigned u = keys[j];
        if ((u >> 16) <= bound16) {
            int p = atomicAdd(&s_ncand, 1);
            if (p < CAP) cand[p] = (((unsigned long long)u) << 32) | (unsigned)j;
        }
    }
    __syncthreads();
    const int nc = s_ncand;

    if (nc <= CAP) {
        if (tid < 64) {
            unsigned long long c[4];
#pragma unroll
            for (int q = 0; q < 4; ++q) { int i = tid + 64 * q; c[q] = (i < nc) ? cand[i] : ~0ull; }
            for (int it = 0; it < KNN; ++it) {
                unsigned long long g = umin64(umin64(c[0], c[1]), umin64(c[2], c[3]));
#pragma unroll
                for (int o = 1; o < 64; o <<= 1) g = umin64(g, __shfl_xor(g, o));
                if (tid == 0) idx_out[(long)row * KNN + it] = (int)(unsigned)(g & 0xFFFFFFFFull);
#pragma unroll
                for (int q = 0; q < 4; ++q) if (c[q] == g) c[q] = ~0ull;   // u64 unique (idx in low bits)
            }
        }
    } else {
        // exact fallback (massive ties) — never expected on this data
        for (int it = 0; it < KNN; ++it) {
            unsigned long long best = ~0ull;
            for (int m = 0; m < NPTS / 256; ++m) {
                int j = tid + 256 * m;
                best = umin64(best, (((unsigned long long)keys[j]) << 32) | (unsigned)j);
            }
#pragma unroll
            for (int o = 1; o < 64; o <<= 1) best = umin64(best, __shfl_xor(best, o));
            if ((tid & 63) == 0) wred[tid >> 6] = best;
            __syncthreads();
            unsigned long long g = umin64(umin64(wred[0], wred[1]), umin64(wred[2], wred[3]));
            int j = (int)(unsigned)(g & 0xFFFFFFFFull);
            if (tid == 0) idx_out[(long)row * KNN + it] = j;
            __syncthreads();
            if (tid == (j & 255)) keys[j] = 0xFFFFFFFFu;
            __syncthreads();
        }
    }
}

// ---------------- erosion edge-conv (fp32, order-free exact) ----------------
template<int F, int C>
__global__ void erode_kernel(const float* __restrict__ X, int ld, const int* __restrict__ idx,
                             const float* __restrict__ w, float* __restrict__ out, int ldo) {
    __shared__ int nidx[KNN];
    __shared__ float neigh[KNN * C];
    const int tid = threadIdx.x;
    const int row = blockIdx.x;
    if (tid < KNN) nidx[tid] = idx[row * KNN + tid];
    __syncthreads();
    for (int t = tid; t < KNN * C; t += blockDim.x) {
        int k = t / C, c = t % C;
        neigh[t] = X[(long)nidx[k] * ld + c];
    }
    __syncthreads();
    if (tid < F * C) {
        int f = tid / C, c = tid % C;
        float m = neigh[c] - w[f * KNN * C + c];
        for (int k = 1; k < KNN; ++k)
            m = fminf(m, neigh[k * C + c] - w[(f * KNN + k) * C + c]);
        out[(long)row * ldo + tid] = m;
    }
}

// ---------------- fp32 GEMM + bias (+ReLU): ascending-k fmaf chain ----------------
template<int RELU>
__global__ __launch_bounds__(256) void gemm_kernel(const float* __restrict__ A, const float* __restrict__ B,
                                                   const float* __restrict__ bias, float* __restrict__ Cm,
                                                   int K, int N) {
    __shared__ float As[16][68];
    __shared__ float Bs[16][68];
    const int tid = threadIdx.x;
    const int i0 = blockIdx.y * 64, j0 = blockIdx.x * 64;
    const int ty = tid >> 4, tx = tid & 15;
    float acc[4][4];
#pragma unroll
    for (int a = 0; a < 4; ++a)
#pragma unroll
        for (int b = 0; b < 4; ++b) acc[a][b] = 0.f;

    for (int k0 = 0; k0 < K; k0 += 16) {
#pragma unroll
        for (int q = 0; q < 4; ++q) {
            int t = tid + 256 * q;
            int r = t >> 4, c = t & 15;
            As[c][r] = (k0 + c < K) ? A[(long)(i0 + r) * K + k0 + c] : 0.f;
            int n = t & 63, kk = t >> 6;
            Bs[kk][n] = (k0 + kk < K && j0 + n < N) ? B[(long)(k0 + kk) * N + j0 + n] : 0.f;
        }
        __syncthreads();
#pragma unroll
        for (int kk = 0; kk < 16; ++kk) {
            float4 a4 = *(const float4*)&As[kk][ty * 4];
            float4 b4 = *(const float4*)&Bs[kk][tx * 4];
            float av[4] = {a4.x, a4.y, a4.z, a4.w};
            float bv[4] = {b4.x, b4.y, b4.z, b4.w};
#pragma unroll
            for (int ii = 0; ii < 4; ++ii)
#pragma unroll
                for (int jj = 0; jj < 4; ++jj)
                    acc[ii][jj] = fmaf(av[ii], bv[jj], acc[ii][jj]);
        }
        __syncthreads();
    }

#pragma unroll
    for (int ii = 0; ii < 4; ++ii) {
        int i = i0 + ty * 4 + ii;
#pragma unroll
        for (int jj = 0; jj < 4; ++jj) {
            int j = j0 + tx * 4 + jj;
            if (j < N) {
                float v = acc[ii][jj] + bias[j];
                if (RELU) v = fmaxf(v, 0.f);
                Cm[(long)i * N + j] = v;
            }
        }
    }
}

// ---------------- log_softmax over 40 cols, wave per row, in place ----------------
__global__ void logsoftmax_kernel(float* __restrict__ out) {
    const int lane = threadIdx.x & 63;
    const int wid = threadIdx.x >> 6;
    const int row = blockIdx.x * 4 + wid;
    float* o = out + (long)row * 40;
    float v = (lane < 40) ? o[lane] : -INFINITY;
    float m = v;
#pragma unroll
    for (int off = 1; off < 64; off <<= 1) m = fmaxf(m, __shfl_xor(m, off));
    float e = (lane < 40) ? expf(v - m) : 0.f;
    float s = e;
#pragma unroll
    for (int off = 1; off < 64; off <<= 1) s += __shfl_xor(s, off);
    float r = (v - m) - logf(s);
    if (lane < 40) o[lane] = r;
}

extern "C" void kernel_launch(void* const* d_in, const int* in_sizes, int n_in,
                              void* d_out, int out_size, void* d_ws, size_t ws_size,
                              hipStream_t stream) {
    (void)in_sizes; (void)n_in; (void)out_size;
    const float* x     = (const float*)d_in[0];
    const float* w1    = (const float*)d_in[1];
    const float* w2    = (const float*)d_in[2];
    const float* w3    = (const float*)d_in[3];
    const float* lin1w = (const float*)d_in[4];
    const float* lin1b = (const float*)d_in[5];
    const float* wa    = (const float*)d_in[6];
    const float* ba    = (const float*)d_in[7];
    const float* wb    = (const float*)d_in[8];
    const float* bb    = (const float*)d_in[9];
    const float* wo    = (const float*)d_in[10];
    const float* bo    = (const float*)d_in[11];
    float* outp = (float*)d_out;

    // ---- ws_size-adaptive layout ----
    char* ws = (char*)d_ws;
    size_t off = 0;
    auto take = [&](size_t bytes) { char* p = ws + off; off += (bytes + 255) & ~(size_t)255; return p; };
    float* x2  = (float*)take((size_t)NPTS * 4);
    int*   idx = (int*)  take((size_t)NPTS * KNN * 4);
    float* h0  = (float*)take((size_t)NPTS * 420 * 4);
    size_t rest = (ws_size > off) ? (ws_size - off) : 0;
    char*  scratch = ws + off;

    int cr = (int)(rest / ((size_t)NPTS * 4));   // fp32 dist chunk rows
    if (cr > 2048) cr = 2048;                    // 64 MB chunk: keep topk re-read L3-resident
    cr &= ~63;
    if (cr < 64) cr = 64;
    float* dist = (float*)scratch;

    int mr = (int)(rest / 5632);                 // fp32 MLP chunk rows
    if (mr > NPTS) mr = NPTS;
    mr &= ~63;
    if (mr < 64) mr = 64;

    dim3 b256(256);
    dim3 grow(NPTS);

    // ---- stage 1: knn(x, C=3) -> erode -> x1 = h0[:, 0:60]
    rowsq_np_kernel<3><<<dim3(32), b256, 0, stream>>>(x, 3, x2);
    for (int r0 = 0; r0 < NPTS; r0 += cr) {
        int rows = (NPTS - r0 < cr) ? (NPTS - r0) : cr;
        dist_kernel<3><<<dim3(128, rows / 64), b256, 0, stream>>>(x, 3, x2, dist, r0);
        topk_kernel<<<dim3(rows), b256, 0, stream>>>(dist, idx, r0);
    }
    erode_kernel<20, 3><<<grow, dim3(64), 0, stream>>>(x, 3, idx, w1, h0 + 0, 420);

    // ---- stage 2: knn(x1, C=60) -> erode -> x2f = h0[:, 60:180]
    rowsq_np_kernel<60><<<dim3(32), b256, 0, stream>>>(h0, 420, x2);
    for (int r0 = 0; r0 < NPTS; r0 += cr) {
        int rows = (NPTS - r0 < cr) ? (NPTS - r0) : cr;
        dist_kernel<60><<<dim3(128, rows / 64), b256, 0, stream>>>(h0, 420, x2, dist, r0);
        topk_kernel<<<dim3(rows), b256, 0, stream>>>(dist, idx, r0);
    }
    erode_kernel<2, 60><<<grow, dim3(128), 0, stream>>>(h0, 420, idx, w2, h0 + 60, 420);

    // ---- stage 3: knn(x2f, C=120) -> erode -> x3 = h0[:, 180:420]
    rowsq_np_kernel<120><<<dim3(32), b256, 0, stream>>>(h0 + 60, 420, x2);
    for (int r0 = 0; r0 < NPTS; r0 += cr) {
        int rows = (NPTS - r0 < cr) ? (NPTS - r0) : cr;
        dist_kernel<120><<<dim3(128, rows / 64), b256, 0, stream>>>(h0 + 60, 420, x2, dist, r0);
        topk_kernel<<<dim3(rows), b256, 0, stream>>>(dist, idx, r0);
    }
    erode_kernel<2, 120><<<grow, dim3(256), 0, stream>>>(h0 + 60, 420, idx, w3, h0 + 180, 420);

    // ---- MLP (row-chunked; h1|h2|h3 live in scratch)
    for (int r0 = 0; r0 < NPTS; r0 += mr) {
        int rows = (NPTS - r0 < mr) ? (NPTS - r0) : mr;
        float* h1c = (float*)scratch;
        float* h2c = h1c + (size_t)mr * 1024;
        float* h3c = h2c + (size_t)mr * 256;
        gemm_kernel<1><<<dim3(16, rows / 64), b256, 0, stream>>>(h0 + (long)r0 * 420, lin1w, lin1b, h1c, 420, 1024);
        gemm_kernel<1><<<dim3(4, rows / 64), b256, 0, stream>>>(h1c, wa, ba, h2c, 1024, 256);
        gemm_kernel<1><<<dim3(2, rows / 64), b256, 0, stream>>>(h2c, wb, bb, h3c, 256, 128);
        gemm_kernel<0><<<dim3(1, rows / 64), b256, 0, stream>>>(h3c, wo, bo, outp + (long)r0 * 40, 128, 40);
        logsoftmax_kernel<<<dim3(rows / 4), b256, 0, stream>>>(outp + (long)r0 * 40);
    }
}

// Round 6
// 1575.105 us; speedup vs baseline: 1.4128x; 1.4128x over previous
//
#include <hip/hip_runtime.h>
#include <math.h>

#define NPTS 8192
#define KNN 20
#define CAP 256

static __device__ __forceinline__ unsigned long long umin64(unsigned long long a, unsigned long long b) {
    return a < b ? a : b;
}

// ---------------- row squared norms: bit-faithful replica of np.sum(x*x, -1) ----------------
template<int C>
__global__ void rowsq_np_kernel(const float* __restrict__ X, int ld, float* __restrict__ x2) {
#pragma clang fp contract(off)
    int i = blockIdx.x * blockDim.x + threadIdx.x;
    if (i >= NPTS) return;
    const float* row = X + (long)i * ld;
    float res;
    if (C < 8) {
        res = 0.f;
        for (int c = 0; c < C; ++c) res += row[c] * row[c];
    } else {
        float r[8];
#pragma unroll
        for (int j = 0; j < 8; ++j) r[j] = row[j] * row[j];
        int p = 8;
        for (; p < C - (C % 8); p += 8)
#pragma unroll
            for (int j = 0; j < 8; ++j) r[j] += row[p + j] * row[p + j];
        res = ((r[0] + r[1]) + (r[2] + r[3])) + ((r[4] + r[5]) + (r[6] + r[7]));
        for (; p < C; ++p) res += row[p] * row[p];
    }
    x2[i] = res;
}

// ---------------- pairwise distance (fp32), BK=32 register-prefetch pipeline ----------------
// RUNTIME C (keeps the compiler from flattening the k0 loop -> bounded VGPRs).
// Bit-identical accumulation to round-4: one fmaf acc per element, k strictly ascending;
// pad lanes contribute fmaf(0,0,acc) == acc exactly. Epilogue formula unchanged.
__global__ __launch_bounds__(256) void dist_kernel(const float* __restrict__ X, int ld, int C,
                                                   const float* __restrict__ x2,
                                                   float* __restrict__ dist, int i0base) {
    __shared__ float As[32][68];
    __shared__ float Bs[32][68];
    const int tid = threadIdx.x;
    const int i0 = i0base + blockIdx.y * 64;
    const int j0 = blockIdx.x * 64;
    const int ty = tid >> 4, tx = tid & 15;
    const int lc = tid & 31, lr = tid >> 5;   // loader: col k0+lc, rows lr+8q

    float ra[8], rb[8];
    float acc[4][4];
#pragma unroll
    for (int a = 0; a < 4; ++a)
#pragma unroll
        for (int b = 0; b < 4; ++b) acc[a][b] = 0.f;

    // prefetch k0 = 0
    {
        const bool v = (lc < C);
#pragma unroll
        for (int q = 0; q < 8; ++q) {
            int r = lr + 8 * q;
            ra[q] = v ? X[(long)(i0 + r) * ld + lc] : 0.f;
            rb[q] = v ? X[(long)(j0 + r) * ld + lc] : 0.f;
        }
    }

    for (int k0 = 0; k0 < C; k0 += 32) {
#pragma unroll
        for (int q = 0; q < 8; ++q) {
            As[lc][lr + 8 * q] = ra[q];
            Bs[lc][lr + 8 * q] = rb[q];
        }
        __syncthreads();
        if (k0 + 32 < C) {
            const bool v = (k0 + 32 + lc < C);
#pragma unroll
            for (int q = 0; q < 8; ++q) {
                int r = lr + 8 * q;
                ra[q] = v ? X[(long)(i0 + r) * ld + k0 + 32 + lc] : 0.f;
                rb[q] = v ? X[(long)(j0 + r) * ld + k0 + 32 + lc] : 0.f;
            }
        }
#pragma unroll
        for (int kk = 0; kk < 32; ++kk) {
            float4 a4 = *(const float4*)&As[kk][ty * 4];
            float4 b4 = *(const float4*)&Bs[kk][tx * 4];
            float av[4] = {a4.x, a4.y, a4.z, a4.w};
            float bv[4] = {b4.x, b4.y, b4.z, b4.w};
#pragma unroll
            for (int ii = 0; ii < 4; ++ii)
#pragma unroll
                for (int jj = 0; jj < 4; ++jj)
                    acc[ii][jj] = fmaf(av[ii], bv[jj], acc[ii][jj]);
        }
        __syncthreads();
    }

    float xj[4];
#pragma unroll
    for (int jj = 0; jj < 4; ++jj) xj[jj] = x2[j0 + tx * 4 + jj];
#pragma unroll
    for (int ii = 0; ii < 4; ++ii) {
        int rloc = blockIdx.y * 64 + ty * 4 + ii;
        float xi = x2[i0base + rloc];
        float4 o;
        o.x = (xi + xj[0]) - 2.f * acc[ii][0];
        o.y = (xi + xj[1]) - 2.f * acc[ii][1];
        o.z = (xi + xj[2]) - 2.f * acc[ii][2];
        o.w = (xi + xj[3]) - 2.f * acc[ii][3];
        *(float4*)&dist[(long)rloc * NPTS + j0 + tx * 4] = o;
    }
}

// ---------------- exact top-K via 2-level radix-select (ascending by (dist,index)) ----------------
// Per-wave sub-histograms (hist[4][256]) cut same-bin LDS-atomic serialization 4x.
__global__ __launch_bounds__(256) void topk_kernel(const float* __restrict__ dist, int* __restrict__ idx_out,
                                                   int rowbase) {
    __shared__ unsigned int keys[NPTS];
    __shared__ unsigned int hist[4][256];
    __shared__ unsigned long long cand[CAP];
    __shared__ int s_b1, s_cb1, s_b2, s_ncand;
    __shared__ unsigned long long wred[4];
    const int tid = threadIdx.x;
    const int wid = tid >> 6;
    const int row = rowbase + blockIdx.x;
    const float* drow = dist + (long)blockIdx.x * NPTS;

    for (int m = 0; m < NPTS / 256; ++m) {
        int j = tid + 256 * m;
        unsigned u = __float_as_uint(drow[j]);
        keys[j] = (u & 0x80000000u) ? ~u : (u | 0x80000000u);
    }
    {
        unsigned* hf = &hist[0][0];
        for (int t = tid; t < 1024; t += 256) hf[t] = 0;
    }
    __syncthreads();

    for (int m = 0; m < NPTS / 256; ++m)
        atomicAdd(&hist[wid][keys[tid + 256 * m] >> 24], 1u);
    __syncthreads();

    if (tid < 64) {
        unsigned c[4];
#pragma unroll
        for (int q = 0; q < 4; ++q)
            c[q] = hist[0][tid * 4 + q] + hist[1][tid * 4 + q] + hist[2][tid * 4 + q] + hist[3][tid * 4 + q];
        unsigned gs = c[0] + c[1] + c[2] + c[3];
        unsigned pre = gs;
#pragma unroll
        for (int o = 1; o < 64; o <<= 1) { unsigned v = __shfl_up(pre, (unsigned)o); if (tid >= o) pre += v; }
        unsigned cb = pre - gs;
        int b = -1; unsigned cbv = 0;
#pragma unroll
        for (int q = 0; q < 4; ++q) {
            if (b < 0 && cb < KNN && cb + c[q] >= KNN) { b = tid * 4 + q; cbv = cb; }
            cb += c[q];
        }
        if (b >= 0) { s_b1 = b; s_cb1 = (int)cbv; }
    }
    __syncthreads();
    const int b1 = s_b1, cb1 = s_cb1;
    {
        unsigned* hf = &hist[0][0];
        for (int t = tid; t < 1024; t += 256) hf[t] = 0;
    }
    __syncthreads();

    for (int m = 0; m < NPTS / 256; ++m) {
        unsigned u = keys[tid + 256 * m];
        if ((int)(u >> 24) == b1) atomicAdd(&hist[wid][(u >> 16) & 0xFFu], 1u);
    }
    __syncthreads();

    if (tid < 64) {
        const unsigned rank2 = (unsigned)(KNN - cb1);   // >=1
        unsigned c[4];
#pragma unroll
        for (int q = 0; q < 4; ++q)
            c[q] = hist[0][tid * 4 + q] + hist[1][tid * 4 + q] + hist[2][tid * 4 + q] + hist[3][tid * 4 + q];
        unsigned gs = c[0] + c[1] + c[2] + c[3];
        unsigned pre = gs;
#pragma unroll
        for (int o = 1; o < 64; o <<= 1) { unsigned v = __shfl_up(pre, (unsigned)o); if (tid >= o) pre += v; }
        unsigned cb = pre - gs;
        int b = -1;
#pragma unroll
        for (int q = 0; q < 4; ++q) {
            if (b < 0 && cb < rank2 && cb + c[q] >= rank2) b = tid * 4 + q;
            cb += c[q];
        }
        if (b >= 0) s_b2 = b;
        if (tid == 0) s_ncand = 0;
    }
    __syncthreads();
    const unsigned bound16 = ((unsigned)b1 << 8) | (unsigned)s_b2;

    for (int m = 0; m < NPTS / 256; ++m) {
        int j = tid + 256 * m;
        unsigned u = keys[j];
        if ((u >> 16) <= bound16) {
            int p = atomicAdd(&s_ncand, 1);
            if (p < CAP) cand[p] = (((unsigned long long)u) << 32) | (unsigned)j;
        }
    }
    __syncthreads();
    const int nc = s_ncand;

    if (nc <= CAP) {
        if (tid < 64) {
            unsigned long long c[4];
#pragma unroll
            for (int q = 0; q < 4; ++q) { int i = tid + 64 * q; c[q] = (i < nc) ? cand[i] : ~0ull; }
            for (int it = 0; it < KNN; ++it) {
                unsigned long long g = umin64(umin64(c[0], c[1]), umin64(c[2], c[3]));
#pragma unroll
                for (int o = 1; o < 64; o <<= 1) g = umin64(g, __shfl_xor(g, o));
                if (tid == 0) idx_out[(long)row * KNN + it] = (int)(unsigned)(g & 0xFFFFFFFFull);
#pragma unroll
                for (int q = 0; q < 4; ++q) if (c[q] == g) c[q] = ~0ull;
            }
        }
    } else {
        // exact fallback (massive ties) — not expected on this data
        for (int it = 0; it < KNN; ++it) {
            unsigned long long best = ~0ull;
            for (int m = 0; m < NPTS / 256; ++m) {
                int j = tid + 256 * m;
                best = umin64(best, (((unsigned long long)keys[j]) << 32) | (unsigned)j);
            }
#pragma unroll
            for (int o = 1; o < 64; o <<= 1) best = umin64(best, __shfl_xor(best, o));
            if ((tid & 63) == 0) wred[tid >> 6] = best;
            __syncthreads();
            unsigned long long g = umin64(umin64(wred[0], wred[1]), umin64(wred[2], wred[3]));
            int j = (int)(unsigned)(g & 0xFFFFFFFFull);
            if (tid == 0) idx_out[(long)row * KNN + it] = j;
            __syncthreads();
            if (tid == (j & 255)) keys[j] = 0xFFFFFFFFu;
            __syncthreads();
        }
    }
}

// ---------------- erosion edge-conv (fp32, order-free exact) ----------------
template<int F, int C>
__global__ void erode_kernel(const float* __restrict__ X, int ld, const int* __restrict__ idx,
                             const float* __restrict__ w, float* __restrict__ out, int ldo) {
    __shared__ int nidx[KNN];
    __shared__ float neigh[KNN * C];
    const int tid = threadIdx.x;
    const int row = blockIdx.x;
    if (tid < KNN) nidx[tid] = idx[row * KNN + tid];
    __syncthreads();
    for (int t = tid; t < KNN * C; t += blockDim.x) {
        int k = t / C, c = t % C;
        neigh[t] = X[(long)nidx[k] * ld + c];
    }
    __syncthreads();
    if (tid < F * C) {
        int f = tid / C, c = tid % C;
        float m = neigh[c] - w[f * KNN * C + c];
        for (int k = 1; k < KNN; ++k)
            m = fminf(m, neigh[k * C + c] - w[(f * KNN + k) * C + c]);
        out[(long)row * ldo + tid] = m;
    }
}

// ---------------- fp32 GEMM + bias (+ReLU), BK=32 register-prefetch pipeline ----------------
// Same ascending-k fmaf chain as round 4 (bit-identical); pipelining only changes scheduling.
template<int RELU>
__global__ __launch_bounds__(256) void gemm_kernel(const float* __restrict__ A, const float* __restrict__ B,
                                                   const float* __restrict__ bias, float* __restrict__ Cm,
                                                   int K, int N) {
    __shared__ float As[32][68];
    __shared__ float Bs[32][68];
    const int tid = threadIdx.x;
    const int i0 = blockIdx.y * 64, j0 = blockIdx.x * 64;
    const int ty = tid >> 4, tx = tid & 15;
    const int la_c = tid & 31, la_r = tid >> 5;   // A: rows la_r+8q, col k0+la_c
    const int lb_n = tid & 63, lb_k = tid >> 6;   // B: kk = lb_k+4q, col j0+lb_n

    float ra[8], rb[8];
    float acc[4][4];
#pragma unroll
    for (int a = 0; a < 4; ++a)
#pragma unroll
        for (int b = 0; b < 4; ++b) acc[a][b] = 0.f;

    {
        const bool bn = (j0 + lb_n < N);
#pragma unroll
        for (int q = 0; q < 8; ++q) {
            int r = la_r + 8 * q;
            ra[q] = (la_c < K) ? A[(long)(i0 + r) * K + la_c] : 0.f;
            int kk = lb_k + 4 * q;
            rb[q] = (kk < K && bn) ? B[(long)kk * N + j0 + lb_n] : 0.f;
        }
    }

    for (int k0 = 0; k0 < K; k0 += 32) {
#pragma unroll
        for (int q = 0; q < 8; ++q) {
            As[la_c][la_r + 8 * q] = ra[q];
            Bs[lb_k + 4 * q][lb_n] = rb[q];
        }
        __syncthreads();
        if (k0 + 32 < K) {
            const bool bn = (j0 + lb_n < N);
#pragma unroll
            for (int q = 0; q < 8; ++q) {
                int r = la_r + 8 * q;
                ra[q] = (k0 + 32 + la_c < K) ? A[(long)(i0 + r) * K + k0 + 32 + la_c] : 0.f;
                int kk = k0 + 32 + lb_k + 4 * q;
                rb[q] = (kk < K && bn) ? B[(long)kk * N + j0 + lb_n] : 0.f;
            }
        }
#pragma unroll
        for (int kk = 0; kk < 32; ++kk) {
            float4 a4 = *(const float4*)&As[kk][ty * 4];
            float4 b4 = *(const float4*)&Bs[kk][tx * 4];
            float av[4] = {a4.x, a4.y, a4.z, a4.w};
            float bv[4] = {b4.x, b4.y, b4.z, b4.w};
#pragma unroll
            for (int ii = 0; ii < 4; ++ii)
#pragma unroll
                for (int jj = 0; jj < 4; ++jj)
                    acc[ii][jj] = fmaf(av[ii], bv[jj], acc[ii][jj]);
        }
        __syncthreads();
    }

#pragma unroll
    for (int ii = 0; ii < 4; ++ii) {
        int i = i0 + ty * 4 + ii;
#pragma unroll
        for (int jj = 0; jj < 4; ++jj) {
            int j = j0 + tx * 4 + jj;
            if (j < N) {
                float v = acc[ii][jj] + bias[j];
                if (RELU) v = fmaxf(v, 0.f);
                Cm[(long)i * N + j] = v;
            }
        }
    }
}

// ---------------- log_softmax over 40 cols, wave per row, in place ----------------
__global__ void logsoftmax_kernel(float* __restrict__ out) {
    const int lane = threadIdx.x & 63;
    const int wid = threadIdx.x >> 6;
    const int row = blockIdx.x * 4 + wid;
    float* o = out + (long)row * 40;
    float v = (lane < 40) ? o[lane] : -INFINITY;
    float m = v;
#pragma unroll
    for (int off = 1; off < 64; off <<= 1) m = fmaxf(m, __shfl_xor(m, off));
    float e = (lane < 40) ? expf(v - m) : 0.f;
    float s = e;
#pragma unroll
    for (int off = 1; off < 64; off <<= 1) s += __shfl_xor(s, off);
    float r = (v - m) - logf(s);
    if (lane < 40) o[lane] = r;
}

extern "C" void kernel_launch(void* const* d_in, const int* in_sizes, int n_in,
                              void* d_out, int out_size, void* d_ws, size_t ws_size,
                              hipStream_t stream) {
    (void)in_sizes; (void)n_in; (void)out_size;
    const float* x     = (const float*)d_in[0];
    const float* w1    = (const float*)d_in[1];
    const float* w2    = (const float*)d_in[2];
    const float* w3    = (const float*)d_in[3];
    const float* lin1w = (const float*)d_in[4];
    const float* lin1b = (const float*)d_in[5];
    const float* wa    = (const float*)d_in[6];
    const float* ba    = (const float*)d_in[7];
    const float* wb    = (const float*)d_in[8];
    const float* bb    = (const float*)d_in[9];
    const float* wo    = (const float*)d_in[10];
    const float* bo    = (const float*)d_in[11];
    float* outp = (float*)d_out;

    // ---- ws_size-adaptive layout ----
    char* ws = (char*)d_ws;
    size_t off = 0;
    auto take = [&](size_t bytes) { char* p = ws + off; off += (bytes + 255) & ~(size_t)255; return p; };
    float* x2  = (float*)take((size_t)NPTS * 4);
    int*   idx = (int*)  take((size_t)NPTS * KNN * 4);
    float* h0  = (float*)take((size_t)NPTS * 420 * 4);
    size_t rest = (ws_size > off) ? (ws_size - off) : 0;
    char*  scratch = ws + off;

    int cr = (int)(rest / ((size_t)NPTS * 4));   // fp32 dist chunk rows
    if (cr > 4096) cr = 4096;                    // 128 MB chunk: topk re-read stays L3-resident
    cr &= ~63;
    if (cr < 64) cr = 64;
    float* dist = (float*)scratch;

    int mr = (int)(rest / 5632);                 // fp32 MLP chunk rows
    if (mr > NPTS) mr = NPTS;
    mr &= ~63;
    if (mr < 64) mr = 64;

    dim3 b256(256);
    dim3 grow(NPTS);

    // ---- stage 1: knn(x, C=3) -> erode -> x1 = h0[:, 0:60]
    rowsq_np_kernel<3><<<dim3(32), b256, 0, stream>>>(x, 3, x2);
    for (int r0 = 0; r0 < NPTS; r0 += cr) {
        int rows = (NPTS - r0 < cr) ? (NPTS - r0) : cr;
        dist_kernel<<<dim3(128, rows / 64), b256, 0, stream>>>(x, 3, 3, x2, dist, r0);
        topk_kernel<<<dim3(rows), b256, 0, stream>>>(dist, idx, r0);
    }
    erode_kernel<20, 3><<<grow, dim3(64), 0, stream>>>(x, 3, idx, w1, h0 + 0, 420);

    // ---- stage 2: knn(x1, C=60) -> erode -> x2f = h0[:, 60:180]
    rowsq_np_kernel<60><<<dim3(32), b256, 0, stream>>>(h0, 420, x2);
    for (int r0 = 0; r0 < NPTS; r0 += cr) {
        int rows = (NPTS - r0 < cr) ? (NPTS - r0) : cr;
        dist_kernel<<<dim3(128, rows / 64), b256, 0, stream>>>(h0, 420, 60, x2, dist, r0);
        topk_kernel<<<dim3(rows), b256, 0, stream>>>(dist, idx, r0);
    }
    erode_kernel<2, 60><<<grow, dim3(128), 0, stream>>>(h0, 420, idx, w2, h0 + 60, 420);

    // ---- stage 3: knn(x2f, C=120) -> erode -> x3 = h0[:, 180:420]
    rowsq_np_kernel<120><<<dim3(32), b256, 0, stream>>>(h0 + 60, 420, x2);
    for (int r0 = 0; r0 < NPTS; r0 += cr) {
        int rows = (NPTS - r0 < cr) ? (NPTS - r0) : cr;
        dist_kernel<<<dim3(128, rows / 64), b256, 0, stream>>>(h0 + 60, 420, 120, x2, dist, r0);
        topk_kernel<<<dim3(rows), b256, 0, stream>>>(dist, idx, r0);
    }
    erode_kernel<2, 120><<<grow, dim3(256), 0, stream>>>(h0 + 60, 420, idx, w3, h0 + 180, 420);

    // ---- MLP (row-chunked; h1|h2|h3 live in scratch)
    for (int r0 = 0; r0 < NPTS; r0 += mr) {
        int rows = (NPTS - r0 < mr) ? (NPTS - r0) : mr;
        float* h1c = (float*)scratch;
        float* h2c = h1c + (size_t)mr * 1024;
        float* h3c = h2c + (size_t)mr * 256;
        gemm_kernel<1><<<dim3(16, rows / 64), b256, 0, stream>>>(h0 + (long)r0 * 420, lin1w, lin1b, h1c, 420, 1024);
        gemm_kernel<1><<<dim3(4, rows / 64), b256, 0, stream>>>(h1c, wa, ba, h2c, 1024, 256);
        gemm_kernel<1><<<dim3(2, rows / 64), b256, 0, stream>>>(h2c, wb, bb, h3c, 256, 128);
        gemm_kernel<0><<<dim3(1, rows / 64), b256, 0, stream>>>(h3c, wo, bo, outp + (long)r0 * 40, 128, 40);
        logsoftmax_kernel<<<dim3(rows / 4), b256, 0, stream>>>(outp + (long)r0 * 40);
    }
}

// Round 7
// 1466.528 us; speedup vs baseline: 1.5174x; 1.0740x over previous
//
#include <hip/hip_runtime.h>
#include <math.h>

#define NPTS 8192
#define KNN 20
#define CAP 256

static __device__ __forceinline__ unsigned long long umin64(unsigned long long a, unsigned long long b) {
    return a < b ? a : b;
}

// ---------------- row squared norms: bit-faithful replica of np.sum(x*x, -1) ----------------
template<int C>
__global__ void rowsq_np_kernel(const float* __restrict__ X, int ld, float* __restrict__ x2) {
#pragma clang fp contract(off)
    int i = blockIdx.x * blockDim.x + threadIdx.x;
    if (i >= NPTS) return;
    const float* row = X + (long)i * ld;
    float res;
    if (C < 8) {
        res = 0.f;
        for (int c = 0; c < C; ++c) res += row[c] * row[c];
    } else {
        float r[8];
#pragma unroll
        for (int j = 0; j < 8; ++j) r[j] = row[j] * row[j];
        int p = 8;
        for (; p < C - (C % 8); p += 8)
#pragma unroll
            for (int j = 0; j < 8; ++j) r[j] += row[p + j] * row[p + j];
        res = ((r[0] + r[1]) + (r[2] + r[3])) + ((r[4] + r[5]) + (r[6] + r[7]));
        for (; p < C; ++p) res += row[p] * row[p];
    }
    x2[i] = res;
}

// ---------------- shared radix-select core (exact top-K ascending by (key,index)) ----------------
// keys[NPTS] in LDS; all 256 threads participate. Identical algorithm to round-6 topk.
__device__ __forceinline__ void radix_select20(unsigned* keys, unsigned (*hist)[256],
                                               unsigned long long* cand, int* scal,
                                               unsigned long long* wred,
                                               long row, int* __restrict__ idx_out) {
    const int tid = threadIdx.x;
    const int wid = tid >> 6;
    // scal: [0]=b1 [1]=cb1 [2]=b2 [3]=ncand
    {
        unsigned* hf = &hist[0][0];
        for (int t = tid; t < 1024; t += 256) hf[t] = 0;
    }
    __syncthreads();
    for (int m = 0; m < NPTS / 256; ++m)
        atomicAdd(&hist[wid][keys[tid + 256 * m] >> 24], 1u);
    __syncthreads();

    if (tid < 64) {
        unsigned c[4];
#pragma unroll
        for (int q = 0; q < 4; ++q)
            c[q] = hist[0][tid * 4 + q] + hist[1][tid * 4 + q] + hist[2][tid * 4 + q] + hist[3][tid * 4 + q];
        unsigned gs = c[0] + c[1] + c[2] + c[3];
        unsigned pre = gs;
#pragma unroll
        for (int o = 1; o < 64; o <<= 1) { unsigned v = __shfl_up(pre, (unsigned)o); if (tid >= o) pre += v; }
        unsigned cb = pre - gs;
        int b = -1; unsigned cbv = 0;
#pragma unroll
        for (int q = 0; q < 4; ++q) {
            if (b < 0 && cb < KNN && cb + c[q] >= KNN) { b = tid * 4 + q; cbv = cb; }
            cb += c[q];
        }
        if (b >= 0) { scal[0] = b; scal[1] = (int)cbv; }
    }
    __syncthreads();
    const int b1 = scal[0], cb1 = scal[1];
    {
        unsigned* hf = &hist[0][0];
        for (int t = tid; t < 1024; t += 256) hf[t] = 0;
    }
    __syncthreads();

    for (int m = 0; m < NPTS / 256; ++m) {
        unsigned u = keys[tid + 256 * m];
        if ((int)(u >> 24) == b1) atomicAdd(&hist[wid][(u >> 16) & 0xFFu], 1u);
    }
    __syncthreads();

    if (tid < 64) {
        const unsigned rank2 = (unsigned)(KNN - cb1);   // >=1
        unsigned c[4];
#pragma unroll
        for (int q = 0; q < 4; ++q)
            c[q] = hist[0][tid * 4 + q] + hist[1][tid * 4 + q] + hist[2][tid * 4 + q] + hist[3][tid * 4 + q];
        unsigned gs = c[0] + c[1] + c[2] + c[3];
        unsigned pre = gs;
#pragma unroll
        for (int o = 1; o < 64; o <<= 1) { unsigned v = __shfl_up(pre, (unsigned)o); if (tid >= o) pre += v; }
        unsigned cb = pre - gs;
        int b = -1;
#pragma unroll
        for (int q = 0; q < 4; ++q) {
            if (b < 0 && cb < rank2 && cb + c[q] >= rank2) b = tid * 4 + q;
            cb += c[q];
        }
        if (b >= 0) scal[2] = b;
        if (tid == 0) scal[3] = 0;
    }
    __syncthreads();
    const unsigned bound16 = ((unsigned)b1 << 8) | (unsigned)scal[2];

    for (int m = 0; m < NPTS / 256; ++m) {
        int j = tid + 256 * m;
        unsigned u = keys[j];
        if ((u >> 16) <= bound16) {
            int p = atomicAdd(&scal[3], 1);
            if (p < CAP) cand[p] = (((unsigned long long)u) << 32) | (unsigned)j;
        }
    }
    __syncthreads();
    const int nc = scal[3];

    if (nc <= CAP) {
        if (tid < 64) {
            unsigned long long c[4];
#pragma unroll
            for (int q = 0; q < 4; ++q) { int i = tid + 64 * q; c[q] = (i < nc) ? cand[i] : ~0ull; }
            for (int it = 0; it < KNN; ++it) {
                unsigned long long g = umin64(umin64(c[0], c[1]), umin64(c[2], c[3]));
#pragma unroll
                for (int o = 1; o < 64; o <<= 1) g = umin64(g, __shfl_xor(g, o));
                if (tid == 0) idx_out[row * KNN + it] = (int)(unsigned)(g & 0xFFFFFFFFull);
#pragma unroll
                for (int q = 0; q < 4; ++q) if (c[q] == g) c[q] = ~0ull;
            }
        }
    } else {
        // exact fallback (massive ties) — not expected on this data
        for (int it = 0; it < KNN; ++it) {
            unsigned long long best = ~0ull;
            for (int m = 0; m < NPTS / 256; ++m) {
                int j = tid + 256 * m;
                best = umin64(best, (((unsigned long long)keys[j]) << 32) | (unsigned)j);
            }
#pragma unroll
            for (int o = 1; o < 64; o <<= 1) best = umin64(best, __shfl_xor(best, o));
            if ((tid & 63) == 0) wred[tid >> 6] = best;
            __syncthreads();
            unsigned long long g = umin64(umin64(wred[0], wred[1]), umin64(wred[2], wred[3]));
            int j = (int)(unsigned)(g & 0xFFFFFFFFull);
            if (tid == 0) idx_out[row * KNN + it] = j;
            __syncthreads();
            if (tid == (j & 255)) keys[j] = 0xFFFFFFFFu;
            __syncthreads();
        }
    }
}

// ---------------- stage-1 fused: C=3 distances + radix top-K, no dist materialization ----------------
// Same per-element arithmetic as the tiled dist kernel: 3-step ascending fmaf dot;
// epilogue (xi+xj)-2*acc (bit-stable: 2*acc exact => same rounding either codegen).
__global__ __launch_bounds__(256) void knn3_fused_kernel(const float* __restrict__ X,
                                                         const float* __restrict__ x2,
                                                         int* __restrict__ idx_out) {
    __shared__ unsigned int keys[NPTS];
    __shared__ unsigned int hist[4][256];
    __shared__ unsigned long long cand[CAP];
    __shared__ int scal[4];
    __shared__ unsigned long long wred[4];
    const int tid = threadIdx.x;
    const int row = blockIdx.x;
    const float xi0 = X[(long)row * 3], xi1 = X[(long)row * 3 + 1], xi2 = X[(long)row * 3 + 2];
    const float x2i = x2[row];

    for (int m = 0; m < NPTS / 256; ++m) {
        int j = tid + 256 * m;
        float accv = 0.f;
        accv = fmaf(xi0, X[(long)j * 3], accv);
        accv = fmaf(xi1, X[(long)j * 3 + 1], accv);
        accv = fmaf(xi2, X[(long)j * 3 + 2], accv);
        float d = (x2i + x2[j]) - 2.f * accv;
        unsigned u = __float_as_uint(d);
        keys[j] = (u & 0x80000000u) ? ~u : (u | 0x80000000u);
    }
    __syncthreads();
    radix_select20(keys, hist, cand, scal, wred, row, idx_out);
}

// ---------------- pairwise distance (fp32), 128x128 tile, 8x8 microtile, BK=16 prefetch ----------------
// Runtime C keeps VGPRs bounded. Per-element single ascending-k fmaf chain (bit-identical).
__global__ __launch_bounds__(256) void dist128_kernel(const float* __restrict__ X, int ld, int C,
                                                      const float* __restrict__ x2,
                                                      float* __restrict__ dist, int i0base) {
    __shared__ float As[16][132];
    __shared__ float Bs[16][132];
    const int tid = threadIdx.x;
    const int i0 = i0base + blockIdx.y * 128;
    const int j0 = blockIdx.x * 128;
    const int ty = tid >> 4, tx = tid & 15;
    const int lc = tid & 15, lr = tid >> 4;   // loader: col k0+lc, rows lr+16q

    float ra[8], rb[8];
    float acc[8][8];
#pragma unroll
    for (int a = 0; a < 8; ++a)
#pragma unroll
        for (int b = 0; b < 8; ++b) acc[a][b] = 0.f;

    {
        const bool v = (lc < C);
#pragma unroll
        for (int q = 0; q < 8; ++q) {
            int r = lr + 16 * q;
            ra[q] = v ? X[(long)(i0 + r) * ld + lc] : 0.f;
            rb[q] = v ? X[(long)(j0 + r) * ld + lc] : 0.f;
        }
    }

    for (int k0 = 0; k0 < C; k0 += 16) {
#pragma unroll
        for (int q = 0; q < 8; ++q) {
            As[lc][lr + 16 * q] = ra[q];
            Bs[lc][lr + 16 * q] = rb[q];
        }
        __syncthreads();
        if (k0 + 16 < C) {
            const bool v = (k0 + 16 + lc < C);
#pragma unroll
            for (int q = 0; q < 8; ++q) {
                int r = lr + 16 * q;
                ra[q] = v ? X[(long)(i0 + r) * ld + k0 + 16 + lc] : 0.f;
                rb[q] = v ? X[(long)(j0 + r) * ld + k0 + 16 + lc] : 0.f;
            }
        }
#pragma unroll
        for (int kk = 0; kk < 16; ++kk) {
            float4 a0 = *(const float4*)&As[kk][ty * 8];
            float4 a1 = *(const float4*)&As[kk][ty * 8 + 4];
            float4 b0 = *(const float4*)&Bs[kk][tx * 8];
            float4 b1 = *(const float4*)&Bs[kk][tx * 8 + 4];
            float av[8] = {a0.x, a0.y, a0.z, a0.w, a1.x, a1.y, a1.z, a1.w};
            float bv[8] = {b0.x, b0.y, b0.z, b0.w, b1.x, b1.y, b1.z, b1.w};
#pragma unroll
            for (int ii = 0; ii < 8; ++ii)
#pragma unroll
                for (int jj = 0; jj < 8; ++jj)
                    acc[ii][jj] = fmaf(av[ii], bv[jj], acc[ii][jj]);
        }
        __syncthreads();
    }

    float xj[8];
#pragma unroll
    for (int jj = 0; jj < 8; ++jj) xj[jj] = x2[j0 + tx * 8 + jj];
#pragma unroll
    for (int ii = 0; ii < 8; ++ii) {
        int rloc = blockIdx.y * 128 + ty * 8 + ii;
        float xi = x2[i0base + rloc];
        float4 o0, o1;
        o0.x = (xi + xj[0]) - 2.f * acc[ii][0];
        o0.y = (xi + xj[1]) - 2.f * acc[ii][1];
        o0.z = (xi + xj[2]) - 2.f * acc[ii][2];
        o0.w = (xi + xj[3]) - 2.f * acc[ii][3];
        o1.x = (xi + xj[4]) - 2.f * acc[ii][4];
        o1.y = (xi + xj[5]) - 2.f * acc[ii][5];
        o1.z = (xi + xj[6]) - 2.f * acc[ii][6];
        o1.w = (xi + xj[7]) - 2.f * acc[ii][7];
        *(float4*)&dist[(long)rloc * NPTS + j0 + tx * 8] = o0;
        *(float4*)&dist[(long)rloc * NPTS + j0 + tx * 8 + 4] = o1;
    }
}

// ---------------- top-K from materialized dist rows ----------------
__global__ __launch_bounds__(256) void topk_kernel(const float* __restrict__ dist, int* __restrict__ idx_out,
                                                   int rowbase) {
    __shared__ unsigned int keys[NPTS];
    __shared__ unsigned int hist[4][256];
    __shared__ unsigned long long cand[CAP];
    __shared__ int scal[4];
    __shared__ unsigned long long wred[4];
    const int tid = threadIdx.x;
    const long row = rowbase + blockIdx.x;
    const float* drow = dist + (long)blockIdx.x * NPTS;

    for (int m = 0; m < NPTS / 256; ++m) {
        int j = tid + 256 * m;
        unsigned u = __float_as_uint(drow[j]);
        keys[j] = (u & 0x80000000u) ? ~u : (u | 0x80000000u);
    }
    __syncthreads();
    radix_select20(keys, hist, cand, scal, wred, row, idx_out);
}

// ---------------- erosion edge-conv (fp32, order-free exact) ----------------
template<int F, int C>
__global__ void erode_kernel(const float* __restrict__ X, int ld, const int* __restrict__ idx,
                             const float* __restrict__ w, float* __restrict__ out, int ldo) {
    __shared__ int nidx[KNN];
    __shared__ float neigh[KNN * C];
    const int tid = threadIdx.x;
    const int row = blockIdx.x;
    if (tid < KNN) nidx[tid] = idx[row * KNN + tid];
    __syncthreads();
    for (int t = tid; t < KNN * C; t += blockDim.x) {
        int k = t / C, c = t % C;
        neigh[t] = X[(long)nidx[k] * ld + c];
    }
    __syncthreads();
    if (tid < F * C) {
        int f = tid / C, c = tid % C;
        float m = neigh[c] - w[f * KNN * C + c];
        for (int k = 1; k < KNN; ++k)
            m = fminf(m, neigh[k * C + c] - w[(f * KNN + k) * C + c]);
        out[(long)row * ldo + tid] = m;
    }
}

// ---------------- fp32 GEMM 128x128 (lin1), BK=16 prefetch, bias+ReLU ----------------
template<int RELU>
__global__ __launch_bounds__(256) void gemm128_kernel(const float* __restrict__ A, const float* __restrict__ B,
                                                      const float* __restrict__ bias, float* __restrict__ Cm,
                                                      int K, int N) {
    __shared__ float As[16][132];
    __shared__ float Bs[16][132];
    const int tid = threadIdx.x;
    const int i0 = blockIdx.y * 128, j0 = blockIdx.x * 128;
    const int ty = tid >> 4, tx = tid & 15;
    const int lc = tid & 15, lr = tid >> 4;       // A loader
    const int lb_n = tid & 127, lb_k = tid >> 7;  // B loader: rows lb_k+2q

    float ra[8], rb[8];
    float acc[8][8];
#pragma unroll
    for (int a = 0; a < 8; ++a)
#pragma unroll
        for (int b = 0; b < 8; ++b) acc[a][b] = 0.f;

    {
        const bool bn = (j0 + lb_n < N);
#pragma unroll
        for (int q = 0; q < 8; ++q) {
            int r = lr + 16 * q;
            ra[q] = (lc < K) ? A[(long)(i0 + r) * K + lc] : 0.f;
            int kk = lb_k + 2 * q;
            rb[q] = (kk < K && bn) ? B[(long)kk * N + j0 + lb_n] : 0.f;
        }
    }

    for (int k0 = 0; k0 < K; k0 += 16) {
#pragma unroll
        for (int q = 0; q < 8; ++q) {
            As[lc][lr + 16 * q] = ra[q];
            Bs[lb_k + 2 * q][lb_n] = rb[q];
        }
        __syncthreads();
        if (k0 + 16 < K) {
            const bool bn = (j0 + lb_n < N);
#pragma unroll
            for (int q = 0; q < 8; ++q) {
                int r = lr + 16 * q;
                ra[q] = (k0 + 16 + lc < K) ? A[(long)(i0 + r) * K + k0 + 16 + lc] : 0.f;
                int kk = k0 + 16 + lb_k + 2 * q;
                rb[q] = (kk < K && bn) ? B[(long)kk * N + j0 + lb_n] : 0.f;
            }
        }
#pragma unroll
        for (int kk = 0; kk < 16; ++kk) {
            float4 a0 = *(const float4*)&As[kk][ty * 8];
            float4 a1 = *(const float4*)&As[kk][ty * 8 + 4];
            float4 b0 = *(const float4*)&Bs[kk][tx * 8];
            float4 b1 = *(const float4*)&Bs[kk][tx * 8 + 4];
            float av[8] = {a0.x, a0.y, a0.z, a0.w, a1.x, a1.y, a1.z, a1.w};
            float bv[8] = {b0.x, b0.y, b0.z, b0.w, b1.x, b1.y, b1.z, b1.w};
#pragma unroll
            for (int ii = 0; ii < 8; ++ii)
#pragma unroll
                for (int jj = 0; jj < 8; ++jj)
                    acc[ii][jj] = fmaf(av[ii], bv[jj], acc[ii][jj]);
        }
        __syncthreads();
    }

#pragma unroll
    for (int ii = 0; ii < 8; ++ii) {
        int i = i0 + ty * 8 + ii;
#pragma unroll
        for (int jj = 0; jj < 8; ++jj) {
            int j = j0 + tx * 8 + jj;
            if (j < N) {
                float v = acc[ii][jj] + bias[j];
                if (RELU) v = fmaxf(v, 0.f);
                Cm[(long)i * N + j] = v;
            }
        }
    }
}

// ---------------- fp32 GEMM 64x64 (layers 2-4), BK=32 prefetch ----------------
template<int RELU>
__global__ __launch_bounds__(256) void gemm_kernel(const float* __restrict__ A, const float* __restrict__ B,
                                                   const float* __restrict__ bias, float* __restrict__ Cm,
                                                   int K, int N) {
    __shared__ float As[32][68];
    __shared__ float Bs[32][68];
    const int tid = threadIdx.x;
    const int i0 = blockIdx.y * 64, j0 = blockIdx.x * 64;
    const int ty = tid >> 4, tx = tid & 15;
    const int la_c = tid & 31, la_r = tid >> 5;
    const int lb_n = tid & 63, lb_k = tid >> 6;

    float ra[8], rb[8];
    float acc[4][4];
#pragma unroll
    for (int a = 0; a < 4; ++a)
#pragma unroll
        for (int b = 0; b < 4; ++b) acc[a][b] = 0.f;

    {
        const bool bn = (j0 + lb_n < N);
#pragma unroll
        for (int q = 0; q < 8; ++q) {
            int r = la_r + 8 * q;
            ra[q] = (la_c < K) ? A[(long)(i0 + r) * K + la_c] : 0.f;
            int kk = lb_k + 4 * q;
            rb[q] = (kk < K && bn) ? B[(long)kk * N + j0 + lb_n] : 0.f;
        }
    }

    for (int k0 = 0; k0 < K; k0 += 32) {
#pragma unroll
        for (int q = 0; q < 8; ++q) {
            As[la_c][la_r + 8 * q] = ra[q];
            Bs[lb_k + 4 * q][lb_n] = rb[q];
        }
        __syncthreads();
        if (k0 + 32 < K) {
            const bool bn = (j0 + lb_n < N);
#pragma unroll
            for (int q = 0; q < 8; ++q) {
                int r = la_r + 8 * q;
                ra[q] = (k0 + 32 + la_c < K) ? A[(long)(i0 + r) * K + k0 + 32 + la_c] : 0.f;
                int kk = k0 + 32 + lb_k + 4 * q;
                rb[q] = (kk < K && bn) ? B[(long)kk * N + j0 + lb_n] : 0.f;
            }
        }
#pragma unroll
        for (int kk = 0; kk < 32; ++kk) {
            float4 a4 = *(const float4*)&As[kk][ty * 4];
            float4 b4 = *(const float4*)&Bs[kk][tx * 4];
            float av[4] = {a4.x, a4.y, a4.z, a4.w};
            float bv[4] = {b4.x, b4.y, b4.z, b4.w};
#pragma unroll
            for (int ii = 0; ii < 4; ++ii)
#pragma unroll
                for (int jj = 0; jj < 4; ++jj)
                    acc[ii][jj] = fmaf(av[ii], bv[jj], acc[ii][jj]);
        }
        __syncthreads();
    }

#pragma unroll
    for (int ii = 0; ii < 4; ++ii) {
        int i = i0 + ty * 4 + ii;
#pragma unroll
        for (int jj = 0; jj < 4; ++jj) {
            int j = j0 + tx * 4 + jj;
            if (j < N) {
                float v = acc[ii][jj] + bias[j];
                if (RELU) v = fmaxf(v, 0.f);
                Cm[(long)i * N + j] = v;
            }
        }
    }
}

// ---------------- log_softmax over 40 cols, wave per row, in place ----------------
__global__ void logsoftmax_kernel(float* __restrict__ out) {
    const int lane = threadIdx.x & 63;
    const int wid = threadIdx.x >> 6;
    const int row = blockIdx.x * 4 + wid;
    float* o = out + (long)row * 40;
    float v = (lane < 40) ? o[lane] : -INFINITY;
    float m = v;
#pragma unroll
    for (int off = 1; off < 64; off <<= 1) m = fmaxf(m, __shfl_xor(m, off));
    float e = (lane < 40) ? expf(v - m) : 0.f;
    float s = e;
#pragma unroll
    for (int off = 1; off < 64; off <<= 1) s += __shfl_xor(s, off);
    float r = (v - m) - logf(s);
    if (lane < 40) o[lane] = r;
}

extern "C" void kernel_launch(void* const* d_in, const int* in_sizes, int n_in,
                              void* d_out, int out_size, void* d_ws, size_t ws_size,
                              hipStream_t stream) {
    (void)in_sizes; (void)n_in; (void)out_size;
    const float* x     = (const float*)d_in[0];
    const float* w1    = (const float*)d_in[1];
    const float* w2    = (const float*)d_in[2];
    const float* w3    = (const float*)d_in[3];
    const float* lin1w = (const float*)d_in[4];
    const float* lin1b = (const float*)d_in[5];
    const float* wa    = (const float*)d_in[6];
    const float* ba    = (const float*)d_in[7];
    const float* wb    = (const float*)d_in[8];
    const float* bb    = (const float*)d_in[9];
    const float* wo    = (const float*)d_in[10];
    const float* bo    = (const float*)d_in[11];
    float* outp = (float*)d_out;

    // ---- ws_size-adaptive layout ----
    char* ws = (char*)d_ws;
    size_t off = 0;
    auto take = [&](size_t bytes) { char* p = ws + off; off += (bytes + 255) & ~(size_t)255; return p; };
    float* x2  = (float*)take((size_t)NPTS * 4);
    int*   idx = (int*)  take((size_t)NPTS * KNN * 4);
    float* h0  = (float*)take((size_t)NPTS * 420 * 4);
    size_t rest = (ws_size > off) ? (ws_size - off) : 0;
    char*  scratch = ws + off;

    int cr = (int)(rest / ((size_t)NPTS * 4));   // fp32 dist chunk rows
    if (cr > 4096) cr = 4096;                    // 128 MB chunk: topk re-read stays L3-resident
    cr &= ~127;
    if (cr < 128) cr = 128;
    float* dist = (float*)scratch;

    int mr = (int)(rest / 5632);                 // fp32 MLP chunk rows
    if (mr > NPTS) mr = NPTS;
    mr &= ~127;
    if (mr < 128) mr = 128;

    dim3 b256(256);
    dim3 grow(NPTS);

    // ---- stage 1: fused knn(x, C=3) -> erode -> x1 = h0[:, 0:60]
    rowsq_np_kernel<3><<<dim3(32), b256, 0, stream>>>(x, 3, x2);
    knn3_fused_kernel<<<grow, b256, 0, stream>>>(x, x2, idx);
    erode_kernel<20, 3><<<grow, dim3(64), 0, stream>>>(x, 3, idx, w1, h0 + 0, 420);

    // ---- stage 2: knn(x1, C=60) -> erode -> x2f = h0[:, 60:180]
    rowsq_np_kernel<60><<<dim3(32), b256, 0, stream>>>(h0, 420, x2);
    for (int r0 = 0; r0 < NPTS; r0 += cr) {
        int rows = (NPTS - r0 < cr) ? (NPTS - r0) : cr;
        dist128_kernel<<<dim3(64, rows / 128), b256, 0, stream>>>(h0, 420, 60, x2, dist, r0);
        topk_kernel<<<dim3(rows), b256, 0, stream>>>(dist, idx, r0);
    }
    erode_kernel<2, 60><<<grow, dim3(128), 0, stream>>>(h0, 420, idx, w2, h0 + 60, 420);

    // ---- stage 3: knn(x2f, C=120) -> erode -> x3 = h0[:, 180:420]
    rowsq_np_kernel<120><<<dim3(32), b256, 0, stream>>>(h0 + 60, 420, x2);
    for (int r0 = 0; r0 < NPTS; r0 += cr) {
        int rows = (NPTS - r0 < cr) ? (NPTS - r0) : cr;
        dist128_kernel<<<dim3(64, rows / 128), b256, 0, stream>>>(h0 + 60, 420, 120, x2, dist, r0);
        topk_kernel<<<dim3(rows), b256, 0, stream>>>(dist, idx, r0);
    }
    erode_kernel<2, 120><<<grow, dim3(256), 0, stream>>>(h0 + 60, 420, idx, w3, h0 + 180, 420);

    // ---- MLP (row-chunked; h1|h2|h3 live in scratch)
    for (int r0 = 0; r0 < NPTS; r0 += mr) {
        int rows = (NPTS - r0 < mr) ? (NPTS - r0) : mr;
        float* h1c = (float*)scratch;
        float* h2c = h1c + (size_t)mr * 1024;
        float* h3c = h2c + (size_t)mr * 256;
        gemm128_kernel<1><<<dim3(8, rows / 128), b256, 0, stream>>>(h0 + (long)r0 * 420, lin1w, lin1b, h1c, 420, 1024);
        gemm_kernel<1><<<dim3(4, rows / 64), b256, 0, stream>>>(h1c, wa, ba, h2c, 1024, 256);
        gemm_kernel<1><<<dim3(2, rows / 64), b256, 0, stream>>>(h2c, wb, bb, h3c, 256, 128);
        gemm_kernel<0><<<dim3(1, rows / 64), b256, 0, stream>>>(h3c, wo, bo, outp + (long)r0 * 40, 128, 40);
        logsoftmax_kernel<<<dim3(rows / 4), b256, 0, stream>>>(outp + (long)r0 * 40);
    }
}